// Round 1
// baseline (2652.593 us; speedup 1.0000x reference)
//
#include <hip/hip_runtime.h>

#define N_NODES  50000
#define E_EDGES  800000
#define E_TOT    850000   // E + N self-loops
#define H_HEADS  2
#define C_DIM    64
#define HC       128      // H*C
#define L_LAYERS 3
#define OUT_DIM  128
#define G_GRAPHS 512
#define NEG_SLOPE 0.2f

// ---- order-preserving float<->uint encoding for atomicMax on floats ----
__device__ __forceinline__ unsigned f2ord(float f) {
    unsigned b = __float_as_uint(f);
    return (b & 0x80000000u) ? ~b : (b | 0x80000000u);
}
__device__ __forceinline__ float ord2f(unsigned u) {
    unsigned b = (u & 0x80000000u) ? (u ^ 0x80000000u) : ~u;
    return __uint_as_float(b);
}
#define ORD_NEG_INF 0x007FFFFFu   // f2ord(-inf)

// ---- h[n][c] = embed[x[n]][c] ----
__global__ void embed_kernel(const int* __restrict__ x, const float* __restrict__ embed,
                             float* __restrict__ h) {
    int i = blockIdx.x * 256 + threadIdx.x;
    if (i >= N_NODES * C_DIM) return;
    int n = i >> 6, c = i & 63;
    h[i] = embed[x[n] * C_DIM + c];
}

// ---- Y[n][c] = (relu)(X[n][:] @ W[:,c] + b[c]), K=64, M out cols ----
template <int M, bool RELU>
__global__ void linear_kernel(const float* __restrict__ X, const float* __restrict__ W,
                              const float* __restrict__ b, float* __restrict__ Y) {
    constexpr int NPB = 256 / M;   // nodes per block
    __shared__ float sX[NPB * 64];
    int tid = threadIdx.x;
    int base = blockIdx.x * NPB;
    if (tid < NPB * 64) {
        int nn = base + (tid >> 6);
        sX[tid] = (nn < N_NODES) ? X[nn * 64 + (tid & 63)] : 0.f;
    }
    __syncthreads();
    int nl = tid / M;
    int c = tid % M;
    int node = base + nl;
    if (node >= N_NODES) return;
    float sum = b[c];
    const float* xrow = &sX[nl * 64];
#pragma unroll
    for (int k = 0; k < 64; k++) sum = fmaf(xrow[k], W[k * M + c], sum);
    if (RELU) sum = fmaxf(sum, 0.f);
    Y[node * M + c] = sum;
}

// ---- per-layer state init ----
__global__ void init_layer_kernel(unsigned* __restrict__ m_ord, float* __restrict__ denom,
                                  float* __restrict__ agg) {
    int i = blockIdx.x * 256 + threadIdx.x;
    if (i < N_NODES * H_HEADS) { m_ord[i] = ORD_NEG_INF; denom[i] = 0.f; }
    if (i < N_NODES * HC) agg[i] = 0.f;
}

__global__ void zero_out_kernel(float* __restrict__ out) {
    int i = blockIdx.x * 256 + threadIdx.x;
    if (i < G_GRAPHS * OUT_DIM) out[i] = 0.f;
}

// ---- pass 1: per-(edge,head) score + segment max.  One 64-lane wave per (edge,head). ----
__global__ void score_kernel(const float* __restrict__ xl, const float* __restrict__ xr,
                             const float* __restrict__ att, const int* __restrict__ srcs,
                             const int* __restrict__ dsts, float* __restrict__ score,
                             unsigned* __restrict__ m_ord) {
    int e = blockIdx.x * 2 + (threadIdx.x >> 7);
    if (e >= E_TOT) return;
    int t = threadIdx.x & 127;           // channel within [H*C]
    int s, d;
    if (e < E_EDGES) { s = srcs[e]; d = dsts[e]; }
    else             { s = d = e - E_EDGES; }
    float v = xl[s * HC + t] + xr[d * HC + t];
    v = (v > 0.f) ? v : NEG_SLOPE * v;
    float sc = v * att[t];
    // full-wave reduction: each 64-lane wave is exactly one (edge, head)
#pragma unroll
    for (int off = 32; off; off >>= 1) sc += __shfl_xor(sc, off, 64);
    if ((threadIdx.x & 63) == 0) {
        int hh = (t >> 6);
        score[e * H_HEADS + hh] = sc;
        atomicMax(&m_ord[d * H_HEADS + hh], f2ord(sc));
    }
}

// ---- pass 2: p = exp(score - m[dst]); denom[dst] += p ----
__global__ void denom_kernel(float* __restrict__ score, const unsigned* __restrict__ m_ord,
                             float* __restrict__ denom, const int* __restrict__ dsts) {
    int idx = blockIdx.x * 256 + threadIdx.x;
    if (idx >= E_TOT * H_HEADS) return;
    int e = idx >> 1, hh = idx & 1;
    int d = (e < E_EDGES) ? dsts[e] : e - E_EDGES;
    float mm = ord2f(m_ord[d * H_HEADS + hh]);
    float p = expf(score[idx] - mm);
    score[idx] = p;                      // overwrite score with p
    atomicAdd(&denom[d * H_HEADS + hh], p);
}

// ---- pass 3: agg[dst] += xl[src] * (p / denom[dst]) ----
__global__ void aggregate_kernel(const float* __restrict__ xl, const float* __restrict__ score_p,
                                 const float* __restrict__ denom, const int* __restrict__ srcs,
                                 const int* __restrict__ dsts, float* __restrict__ agg) {
    int e = blockIdx.x * 2 + (threadIdx.x >> 7);
    if (e >= E_TOT) return;
    int t = threadIdx.x & 127;
    int s, d;
    if (e < E_EDGES) { s = srcs[e]; d = dsts[e]; }
    else             { s = d = e - E_EDGES; }
    int hh = t >> 6;
    float alpha = score_p[e * H_HEADS + hh] / denom[d * H_HEADS + hh];
    atomicAdd(&agg[d * HC + t], xl[s * HC + t] * alpha);
}

// ---- head mean + bias -> next h ----
__global__ void mean_bias_kernel(const float* __restrict__ agg, const float* __restrict__ bias,
                                 float* __restrict__ h) {
    int i = blockIdx.x * 256 + threadIdx.x;
    if (i >= N_NODES * C_DIM) return;
    int n = i >> 6, c = i & 63;
    h[i] = (agg[n * HC + c] + agg[n * HC + 64 + c]) * 0.5f + bias[c];
}

// ---- readout GEMM (K=64 -> 128) fused with per-graph segment sum ----
__global__ void readout_kernel(const float* __restrict__ h, const float* __restrict__ W,
                               const float* __restrict__ b, const int* __restrict__ batch,
                               float* __restrict__ out) {
    __shared__ float sX[2 * 64];
    int tid = threadIdx.x;
    int base = blockIdx.x * 2;
    if (tid < 128) {
        int nn = base + (tid >> 6);
        sX[tid] = (nn < N_NODES) ? h[nn * 64 + (tid & 63)] : 0.f;
    }
    __syncthreads();
    int nl = tid >> 7;
    int c = tid & 127;
    int node = base + nl;
    if (node >= N_NODES) return;
    float sum = b[c];
    const float* xrow = &sX[nl * 64];
#pragma unroll
    for (int k = 0; k < 64; k++) sum = fmaf(xrow[k], W[k * OUT_DIM + c], sum);
    atomicAdd(&out[batch[node] * OUT_DIM + c], sum);
}

extern "C" void kernel_launch(void* const* d_in, const int* in_sizes, int n_in,
                              void* d_out, int out_size, void* d_ws, size_t ws_size,
                              hipStream_t stream) {
    const int*   x        = (const int*)d_in[0];
    const int*   edge     = (const int*)d_in[1];    // [2,E] flat: src row then dst row
    const int*   batch    = (const int*)d_in[2];
    const float* embed    = (const float*)d_in[4];
    const float* lin_W    = (const float*)d_in[5];  // [L,64,64]
    const float* lin_b    = (const float*)d_in[6];  // [L,64]
    const float* gat_Wl   = (const float*)d_in[7];  // [L,64,128]
    const float* gat_bl   = (const float*)d_in[8];  // [L,128]
    const float* gat_Wr   = (const float*)d_in[9];  // [L,64,128]
    const float* gat_br   = (const float*)d_in[10]; // [L,128]
    const float* gat_att  = (const float*)d_in[11]; // [L,2,64]
    const float* gat_bias = (const float*)d_in[12]; // [L,64]
    const float* ro_W     = (const float*)d_in[13]; // [64,128]
    const float* ro_b     = (const float*)d_in[14]; // [128]
    float* out = (float*)d_out;

    const int* srcs = edge;
    const int* dsts = edge + E_EDGES;

    // workspace layout (floats)
    float* h      = (float*)d_ws;                       // N*64
    float* h2     = h   + (size_t)N_NODES * 64;         // N*64
    float* xl     = h2  + (size_t)N_NODES * 64;         // N*128
    float* xr     = xl  + (size_t)N_NODES * HC;         // N*128
    float* agg    = xr  + (size_t)N_NODES * HC;         // N*128
    float* scoreb = agg + (size_t)N_NODES * HC;         // E_TOT*2
    unsigned* m_ord = (unsigned*)(scoreb + (size_t)E_TOT * H_HEADS); // N*2
    float* denom  = (float*)(m_ord + (size_t)N_NODES * H_HEADS);     // N*2

    const int nThreads = 256;
    const int gEmbed  = (N_NODES * C_DIM + 255) / 256;   // 12500
    const int gLin64  = (N_NODES + 3) / 4;               // 12500
    const int gLin128 = (N_NODES + 1) / 2;               // 25000
    const int gInit   = (N_NODES * HC + 255) / 256;      // 25000
    const int gEdge   = (E_TOT + 1) / 2;                 // 425000
    const int gDenom  = (E_TOT * H_HEADS + 255) / 256;   // 6641
    const int gOut    = (G_GRAPHS * OUT_DIM + 255) / 256;

    embed_kernel<<<gEmbed, nThreads, 0, stream>>>(x, embed, h);

    for (int l = 0; l < L_LAYERS; l++) {
        linear_kernel<64, true><<<gLin64, nThreads, 0, stream>>>(
            h, lin_W + (size_t)l * 64 * 64, lin_b + (size_t)l * 64, h2);
        linear_kernel<128, false><<<gLin128, nThreads, 0, stream>>>(
            h2, gat_Wl + (size_t)l * 64 * 128, gat_bl + (size_t)l * 128, xl);
        linear_kernel<128, false><<<gLin128, nThreads, 0, stream>>>(
            h2, gat_Wr + (size_t)l * 64 * 128, gat_br + (size_t)l * 128, xr);
        init_layer_kernel<<<gInit, nThreads, 0, stream>>>(m_ord, denom, agg);
        score_kernel<<<gEdge, nThreads, 0, stream>>>(
            xl, xr, gat_att + (size_t)l * HC, srcs, dsts, scoreb, m_ord);
        denom_kernel<<<gDenom, nThreads, 0, stream>>>(scoreb, m_ord, denom, dsts);
        aggregate_kernel<<<gEdge, nThreads, 0, stream>>>(
            xl, scoreb, denom, srcs, dsts, agg);
        mean_bias_kernel<<<gEmbed, nThreads, 0, stream>>>(
            agg, gat_bias + (size_t)l * 64, h);
    }

    zero_out_kernel<<<gOut, nThreads, 0, stream>>>(out);
    readout_kernel<<<gLin128, nThreads, 0, stream>>>(h, ro_W, ro_b, batch, out);
}

// Round 2
// 1150.269 us; speedup vs baseline: 2.3061x; 2.3061x over previous
//
#include <hip/hip_runtime.h>

#define N_NODES  50000
#define E_EDGES  800000
#define E_TOT    850000   // E + N self-loops
#define H_HEADS  2
#define C_DIM    64
#define HC       128
#define L_LAYERS 3
#define OUT_DIM  128
#define G_GRAPHS 512
#define NEG_SLOPE 0.2f
#define CAP      256      // edges per softmax chunk (max degree here ~40)

// ---- h[n][c] = embed[x[n]][c] ----
__global__ void embed_kernel(const int* __restrict__ x, const float* __restrict__ embed,
                             float* __restrict__ h) {
    int i = blockIdx.x * 256 + threadIdx.x;
    if (i >= N_NODES * C_DIM) return;
    int n = i >> 6, c = i & 63;
    h[i] = embed[x[n] * C_DIM + c];
}

// ---- Y[n][c] = relu(X[n][:] @ W[:,c] + b[c]), K=64, 64 out ----
__global__ void lin64_kernel(const float* __restrict__ X, const float* __restrict__ W,
                             const float* __restrict__ b, float* __restrict__ Y) {
    __shared__ float sX[4 * 64];
    int tid = threadIdx.x;
    int base = blockIdx.x * 4;
    {
        int nn = base + (tid >> 6);
        sX[tid] = (nn < N_NODES) ? X[nn * 64 + (tid & 63)] : 0.f;
    }
    __syncthreads();
    int nl = tid >> 6, c = tid & 63;
    int node = base + nl;
    if (node >= N_NODES) return;
    float sum = b[c];
    const float* xrow = &sX[nl * 64];
#pragma unroll
    for (int k = 0; k < 64; k++) sum = fmaf(xrow[k], W[k * 64 + c], sum);
    Y[node * 64 + c] = fmaxf(sum, 0.f);
}

// ---- fused xl/xr linears, output head-interleaved: xl_i[n*128 + c*2 + h] ----
__global__ void linlr_kernel(const float* __restrict__ X,
                             const float* __restrict__ Wl, const float* __restrict__ bl,
                             const float* __restrict__ Wr, const float* __restrict__ br,
                             float* __restrict__ xli, float* __restrict__ xri) {
    __shared__ float sX[2 * 64];
    int tid = threadIdx.x;
    int base = blockIdx.x * 2;
    if (tid < 128) {
        int nn = base + (tid >> 6);
        sX[tid] = (nn < N_NODES) ? X[nn * 64 + (tid & 63)] : 0.f;
    }
    __syncthreads();
    int nl = tid >> 7, j = tid & 127;
    int node = base + nl;
    if (node >= N_NODES) return;
    float sl = bl[j], sr = br[j];
    const float* xrow = &sX[nl * 64];
#pragma unroll
    for (int k = 0; k < 64; k++) {
        float xv = xrow[k];
        sl = fmaf(xv, Wl[k * 128 + j], sl);
        sr = fmaf(xv, Wr[k * 128 + j], sr);
    }
    int hh = j >> 6, c = j & 63;
    size_t o = (size_t)node * 128 + c * 2 + hh;
    xli[o] = sl;
    xri[o] = sr;
}

// ---- CSR build ----
__global__ void csr_zero_kernel(int* __restrict__ counts) {
    int i = blockIdx.x * 256 + threadIdx.x;
    if (i < N_NODES) counts[i] = 0;
}

__global__ void csr_count_kernel(const int* __restrict__ dsts, int* __restrict__ counts) {
    int e = blockIdx.x * 256 + threadIdx.x;
    if (e >= E_TOT) return;
    int d = (e < E_EDGES) ? dsts[e] : e - E_EDGES;
    atomicAdd(&counts[d], 1);
}

// single block, 1024 threads: exclusive scan of counts -> row_ptr[N+1], write_off
__global__ void csr_scan_kernel(const int* __restrict__ counts, int* __restrict__ row_ptr,
                                int* __restrict__ write_off) {
    __shared__ int ssum[1024];
    int tid = threadIdx.x;
    const int CHUNK = (N_NODES + 1023) / 1024;  // 49
    int start = tid * CHUNK;
    int end = min(start + CHUNK, N_NODES);
    int s = 0;
    for (int i = start; i < end; i++) s += counts[i];
    ssum[tid] = s;
    __syncthreads();
    for (int off = 1; off < 1024; off <<= 1) {
        int v = (tid >= off) ? ssum[tid - off] : 0;
        __syncthreads();
        ssum[tid] += v;
        __syncthreads();
    }
    int run = (tid == 0) ? 0 : ssum[tid - 1];
    for (int i = start; i < end; i++) {
        row_ptr[i] = run;
        write_off[i] = run;
        run += counts[i];
    }
    if (tid == 1023) row_ptr[N_NODES] = run;  // == E_TOT
}

__global__ void csr_scatter_kernel(const int* __restrict__ srcs, const int* __restrict__ dsts,
                                   int* __restrict__ write_off, int* __restrict__ src_sorted) {
    int e = blockIdx.x * 256 + threadIdx.x;
    if (e >= E_TOT) return;
    int s, d;
    if (e < E_EDGES) { s = srcs[e]; d = dsts[e]; }
    else             { s = d = e - E_EDGES; }
    int pos = atomicAdd(&write_off[d], 1);
    src_sorted[pos] = s;
}

// ---- fused GATv2 edge phase: one 64-lane wave per dst node, lane = channel,
// float2 = both heads. Online-softmax over CAP-sized chunks (single chunk in practice).
__global__ void gat_kernel(const float2* __restrict__ xl2, const float2* __restrict__ xr2,
                           const float* __restrict__ att, const int* __restrict__ row_ptr,
                           const int* __restrict__ src_sorted, const float* __restrict__ bias,
                           float* __restrict__ h_out) {
    __shared__ float2 s_sc[4][CAP];
    __shared__ int    s_src[4][CAP];
    int w = threadIdx.x >> 6;
    int d = blockIdx.x * 4 + w;
    if (d >= N_NODES) return;
    int lane = threadIdx.x & 63;
    int r0 = row_ptr[d], r1 = row_ptr[d + 1];
    float2 vr = xr2[(size_t)d * 64 + lane];
    float ax = att[lane], ay = att[64 + lane];

    float mx = -INFINITY, my = -INFINITY;
    float dx = 0.f, dy = 0.f;
    float accx = 0.f, accy = 0.f;

    for (int base = r0; base < r1; base += CAP) {
        int cn = min(CAP, r1 - base);
        // preload src ids (coalesced)
        for (int j = lane; j < cn; j += 64) s_src[w][j] = src_sorted[base + j];
        float cmx = -INFINITY, cmy = -INFINITY;
        // per-edge score (wave reduction); all lanes end with the full dot
        for (int j = 0; j < cn; j++) {
            int s = s_src[w][j];
            float2 vl = xl2[(size_t)s * 64 + lane];
            float vx = vl.x + vr.x, vy = vl.y + vr.y;
            vx = (vx > 0.f) ? vx : NEG_SLOPE * vx;
            vy = (vy > 0.f) ? vy : NEG_SLOPE * vy;
            float sx = vx * ax, sy = vy * ay;
#pragma unroll
            for (int off = 32; off; off >>= 1) {
                sx += __shfl_xor(sx, off, 64);
                sy += __shfl_xor(sy, off, 64);
            }
            if (lane == 0) s_sc[w][j] = make_float2(sx, sy);
            cmx = fmaxf(cmx, sx);
            cmy = fmaxf(cmy, sy);
        }
        // merge chunk max into running max, rescale prior state
        float nmx = fmaxf(mx, cmx), nmy = fmaxf(my, cmy);
        if (nmx > mx && dx != 0.f) { float sc = __expf(mx - nmx); dx *= sc; accx *= sc; }
        if (nmy > my && dy != 0.f) { float sc = __expf(my - nmy); dy *= sc; accy *= sc; }
        mx = nmx; my = nmy;
        // accumulate weighted messages + denominator (weights wave-uniform)
        for (int j = 0; j < cn; j++) {
            float2 sc = s_sc[w][j];
            float wx = __expf(sc.x - mx);
            float wy = __expf(sc.y - my);
            dx += wx; dy += wy;
            int s = s_src[w][j];
            float2 vl = xl2[(size_t)s * 64 + lane];
            accx = fmaf(vl.x, wx, accx);
            accy = fmaf(vl.y, wy, accy);
        }
    }
    h_out[(size_t)d * 64 + lane] = (accx / dx + accy / dy) * 0.5f + bias[lane];
}

__global__ void zero_out_kernel(float* __restrict__ out) {
    int i = blockIdx.x * 256 + threadIdx.x;
    if (i < G_GRAPHS * OUT_DIM) out[i] = 0.f;
}

// ---- readout GEMM (K=64 -> 128) fused with per-graph segment sum ----
__global__ void readout_kernel(const float* __restrict__ h, const float* __restrict__ W,
                               const float* __restrict__ b, const int* __restrict__ batch,
                               float* __restrict__ out) {
    __shared__ float sX[2 * 64];
    int tid = threadIdx.x;
    int base = blockIdx.x * 2;
    if (tid < 128) {
        int nn = base + (tid >> 6);
        sX[tid] = (nn < N_NODES) ? h[nn * 64 + (tid & 63)] : 0.f;
    }
    __syncthreads();
    int nl = tid >> 7;
    int c = tid & 127;
    int node = base + nl;
    if (node >= N_NODES) return;
    float sum = b[c];
    const float* xrow = &sX[nl * 64];
#pragma unroll
    for (int k = 0; k < 64; k++) sum = fmaf(xrow[k], W[k * OUT_DIM + c], sum);
    atomicAdd(&out[batch[node] * OUT_DIM + c], sum);
}

extern "C" void kernel_launch(void* const* d_in, const int* in_sizes, int n_in,
                              void* d_out, int out_size, void* d_ws, size_t ws_size,
                              hipStream_t stream) {
    const int*   x        = (const int*)d_in[0];
    const int*   edge     = (const int*)d_in[1];
    const int*   batch    = (const int*)d_in[2];
    const float* embed    = (const float*)d_in[4];
    const float* lin_W    = (const float*)d_in[5];
    const float* lin_b    = (const float*)d_in[6];
    const float* gat_Wl   = (const float*)d_in[7];
    const float* gat_bl   = (const float*)d_in[8];
    const float* gat_Wr   = (const float*)d_in[9];
    const float* gat_br   = (const float*)d_in[10];
    const float* gat_att  = (const float*)d_in[11];
    const float* gat_bias = (const float*)d_in[12];
    const float* ro_W     = (const float*)d_in[13];
    const float* ro_b     = (const float*)d_in[14];
    float* out = (float*)d_out;

    const int* srcs = edge;
    const int* dsts = edge + E_EDGES;

    // workspace layout
    float* h   = (float*)d_ws;                      // N*64
    float* h2  = h  + (size_t)N_NODES * 64;         // N*64
    float* xl  = h2 + (size_t)N_NODES * 64;         // N*128 (head-interleaved)
    float* xr  = xl + (size_t)N_NODES * HC;         // N*128 (head-interleaved)
    int* counts     = (int*)(xr + (size_t)N_NODES * HC);  // N
    int* row_ptr    = counts + N_NODES;                   // N+1
    int* write_off  = row_ptr + N_NODES + 1;              // N
    int* src_sorted = write_off + N_NODES;                // E_TOT

    const int T = 256;
    const int gEmbed = (N_NODES * C_DIM + 255) / 256;  // 12500
    const int gLin64 = (N_NODES + 3) / 4;              // 12500
    const int gLin2  = (N_NODES + 1) / 2;              // 25000
    const int gNode  = (N_NODES + 255) / 256;          // 196
    const int gEdge  = (E_TOT + 255) / 256;            // 3321
    const int gGat   = (N_NODES + 3) / 4;              // 12500
    const int gOut   = (G_GRAPHS * OUT_DIM + 255) / 256;

    embed_kernel<<<gEmbed, T, 0, stream>>>(x, embed, h);

    // CSR build (graph is layer-invariant)
    csr_zero_kernel<<<gNode, T, 0, stream>>>(counts);
    csr_count_kernel<<<gEdge, T, 0, stream>>>(dsts, counts);
    csr_scan_kernel<<<1, 1024, 0, stream>>>(counts, row_ptr, write_off);
    csr_scatter_kernel<<<gEdge, T, 0, stream>>>(srcs, dsts, write_off, src_sorted);

    for (int l = 0; l < L_LAYERS; l++) {
        lin64_kernel<<<gLin64, T, 0, stream>>>(
            h, lin_W + (size_t)l * 64 * 64, lin_b + (size_t)l * 64, h2);
        linlr_kernel<<<gLin2, T, 0, stream>>>(
            h2, gat_Wl + (size_t)l * 64 * 128, gat_bl + (size_t)l * 128,
            gat_Wr + (size_t)l * 64 * 128, gat_br + (size_t)l * 128, xl, xr);
        gat_kernel<<<gGat, T, 0, stream>>>(
            (const float2*)xl, (const float2*)xr, gat_att + (size_t)l * HC,
            row_ptr, src_sorted, gat_bias + (size_t)l * 64, h);
    }

    zero_out_kernel<<<gOut, T, 0, stream>>>(out);
    readout_kernel<<<gLin2, T, 0, stream>>>(h, ro_W, ro_b, batch, out);
}

// Round 3
// 796.632 us; speedup vs baseline: 3.3298x; 1.4439x over previous
//
#include <hip/hip_runtime.h>

#define N_NODES  50000
#define E_EDGES  800000
#define E_TOT    850000   // E + N self-loops
#define H_HEADS  2
#define C_DIM    64
#define HC       128
#define L_LAYERS 3
#define OUT_DIM  128
#define G_GRAPHS 512
#define NEG_SLOPE 0.2f

// ---- h[n][c] = embed[x[n]][c] ----
__global__ void embed_kernel(const int* __restrict__ x, const float* __restrict__ embed,
                             float* __restrict__ h) {
    int i = blockIdx.x * 256 + threadIdx.x;
    if (i >= N_NODES * C_DIM) return;
    int n = i >> 6, c = i & 63;
    h[i] = embed[x[n] * C_DIM + c];
}

// ---- CSR build ----
__global__ void csr_zero_kernel(int* __restrict__ counts) {
    int i = blockIdx.x * 256 + threadIdx.x;
    if (i < N_NODES) counts[i] = 0;
}

__global__ void csr_count_kernel(const int* __restrict__ dsts, int* __restrict__ counts) {
    int e = blockIdx.x * 256 + threadIdx.x;
    if (e >= E_TOT) return;
    int d = (e < E_EDGES) ? dsts[e] : e - E_EDGES;
    atomicAdd(&counts[d], 1);
}

__global__ void csr_scan_kernel(const int* __restrict__ counts, int* __restrict__ row_ptr,
                                int* __restrict__ write_off) {
    __shared__ int ssum[1024];
    int tid = threadIdx.x;
    const int CHUNK = (N_NODES + 1023) / 1024;  // 49
    int start = tid * CHUNK;
    int end = min(start + CHUNK, N_NODES);
    int s = 0;
    for (int i = start; i < end; i++) s += counts[i];
    ssum[tid] = s;
    __syncthreads();
    for (int off = 1; off < 1024; off <<= 1) {
        int v = (tid >= off) ? ssum[tid - off] : 0;
        __syncthreads();
        ssum[tid] += v;
        __syncthreads();
    }
    int run = (tid == 0) ? 0 : ssum[tid - 1];
    for (int i = start; i < end; i++) {
        row_ptr[i] = run;
        write_off[i] = run;
        run += counts[i];
    }
    if (tid == 1023) row_ptr[N_NODES] = run;
}

__global__ void csr_scatter_kernel(const int* __restrict__ srcs, const int* __restrict__ dsts,
                                   int* __restrict__ write_off, int* __restrict__ src_sorted) {
    int e = blockIdx.x * 256 + threadIdx.x;
    if (e >= E_TOT) return;
    int s, d;
    if (e < E_EDGES) { s = srcs[e]; d = dsts[e]; }
    else             { s = d = e - E_EDGES; }
    int pos = atomicAdd(&write_off[d], 1);
    src_sorted[pos] = s;
}

// ---- fused per-layer linears: h2 = relu(h@W+b); xl = h2@Wl+bl; xr = h2@Wr+br.
// 16 nodes per 256-thread block; h2 lives only in LDS; outputs head-interleaved
// xl[n*128 + c*2 + hh] so gat reads one float2 per (channel, both heads). ----
__global__ void layer_lin_kernel(const float* __restrict__ h,
                                 const float* __restrict__ W, const float* __restrict__ b,
                                 const float* __restrict__ Wl, const float* __restrict__ bl,
                                 const float* __restrict__ Wr, const float* __restrict__ br,
                                 float* __restrict__ xli, float* __restrict__ xri) {
    __shared__ float sH[16 * 64];
    __shared__ float sH2[16 * 64];
    int tid = threadIdx.x;
    int base = blockIdx.x * 16;
#pragma unroll
    for (int i = 0; i < 4; i++) {
        int idx = tid + i * 256;
        int nn = base + (idx >> 6);
        sH[idx] = (nn < N_NODES) ? h[(size_t)nn * 64 + (idx & 63)] : 0.f;
    }
    __syncthreads();
    // phase 2: h2, thread = (col c, node-quad g)
    {
        int c = tid & 63, g = tid >> 6;  // g in 0..3
        float a0 = b[c], a1 = a0, a2 = a0, a3 = a0;
        for (int k = 0; k < 64; k++) {
            float wv = W[k * 64 + c];                 // coalesced, L1-resident
            a0 = fmaf(sH[(g * 4 + 0) * 64 + k], wv, a0);  // LDS broadcast reads
            a1 = fmaf(sH[(g * 4 + 1) * 64 + k], wv, a1);
            a2 = fmaf(sH[(g * 4 + 2) * 64 + k], wv, a2);
            a3 = fmaf(sH[(g * 4 + 3) * 64 + k], wv, a3);
        }
        sH2[(g * 4 + 0) * 64 + c] = fmaxf(a0, 0.f);
        sH2[(g * 4 + 1) * 64 + c] = fmaxf(a1, 0.f);
        sH2[(g * 4 + 2) * 64 + c] = fmaxf(a2, 0.f);
        sH2[(g * 4 + 3) * 64 + c] = fmaxf(a3, 0.f);
    }
    __syncthreads();
    // phase 3: xl/xr, thread = (col j, node-octet gg); 16 FMA per 2 W loads
    {
        int j = tid & 127, gg = tid >> 7;  // gg in 0..1
        float accl[8], accr[8];
#pragma unroll
        for (int n = 0; n < 8; n++) { accl[n] = bl[j]; accr[n] = br[j]; }
        for (int k = 0; k < 64; k++) {
            float wl = Wl[k * 128 + j], wr = Wr[k * 128 + j];
#pragma unroll
            for (int n = 0; n < 8; n++) {
                float hv = sH2[(gg * 8 + n) * 64 + k];  // broadcast
                accl[n] = fmaf(hv, wl, accl[n]);
                accr[n] = fmaf(hv, wr, accr[n]);
            }
        }
        int hh = j >> 6, c = j & 63;
#pragma unroll
        for (int n = 0; n < 8; n++) {
            int node = base + gg * 8 + n;
            if (node < N_NODES) {
                size_t o = (size_t)node * 128 + c * 2 + hh;
                xli[o] = accl[n];
                xri[o] = accr[n];
            }
        }
    }
}

// ---- single-pass fused GATv2 edge phase: one wave per dst node, lane = channel,
// float2 = both heads, flash-style online softmax (score+aggregate in ONE xl read). ----
__global__ void gat_kernel(const float2* __restrict__ xl2, const float2* __restrict__ xr2,
                           const float* __restrict__ att, const int* __restrict__ row_ptr,
                           const int* __restrict__ src_sorted, const float* __restrict__ bias,
                           float* __restrict__ h_out) {
    int w = threadIdx.x >> 6;
    int d = blockIdx.x * 4 + w;
    if (d >= N_NODES) return;
    int lane = threadIdx.x & 63;
    int r0 = row_ptr[d], r1 = row_ptr[d + 1];
    float2 vr = xr2[(size_t)d * 64 + lane];
    float ax = att[lane], ay = att[64 + lane];

    float mx = -INFINITY, my = -INFINITY;
    float dx = 0.f, dy = 0.f;
    float accx = 0.f, accy = 0.f;

    for (int base = r0; base < r1; base += 64) {
        int cn = min(64, r1 - base);
        int idx = (base + lane < r1) ? src_sorted[base + lane] : 0;  // coalesced
        for (int j = 0; j < cn; j++) {
            int s = __shfl(idx, j, 64);
            float2 vl = xl2[(size_t)s * 64 + lane];
            float vx = vl.x + vr.x, vy = vl.y + vr.y;
            vx = (vx > 0.f) ? vx : NEG_SLOPE * vx;
            vy = (vy > 0.f) ? vy : NEG_SLOPE * vy;
            float sx = vx * ax, sy = vy * ay;
#pragma unroll
            for (int off = 32; off; off >>= 1) {
                sx += __shfl_xor(sx, off, 64);
                sy += __shfl_xor(sy, off, 64);
            }
            float nmx = fmaxf(mx, sx), nmy = fmaxf(my, sy);
            float scx = __expf(mx - nmx), scy = __expf(my - nmy);  // -inf-case -> 0
            float wx = __expf(sx - nmx), wy = __expf(sy - nmy);
            accx = fmaf(accx, scx, wx * vl.x);
            accy = fmaf(accy, scy, wy * vl.y);
            dx = fmaf(dx, scx, wx);
            dy = fmaf(dy, scy, wy);
            mx = nmx; my = nmy;
        }
    }
    h_out[(size_t)d * 64 + lane] = (accx / dx + accy / dy) * 0.5f + bias[lane];
}

__global__ void zero_out_kernel(float* __restrict__ out) {
    int i = blockIdx.x * 256 + threadIdx.x;
    if (i < G_GRAPHS * OUT_DIM) out[i] = 0.f;
}

// ---- readout GEMM fused with per-graph segment sum; batch-sorted run grouping ----
__global__ void readout_kernel(const float* __restrict__ h, const float* __restrict__ W,
                               const float* __restrict__ b, const int* __restrict__ batch,
                               float* __restrict__ out) {
    __shared__ float sH[16 * 64];
    __shared__ int sB[16];
    int tid = threadIdx.x;
    int base = blockIdx.x * 16;
#pragma unroll
    for (int i = 0; i < 4; i++) {
        int idx = tid + i * 256;
        int nn = base + (idx >> 6);
        sH[idx] = (nn < N_NODES) ? h[(size_t)nn * 64 + (idx & 63)] : 0.f;
    }
    if (tid < 16) sB[tid] = (base + tid < N_NODES) ? batch[base + tid] : -1;
    __syncthreads();
    int j = tid & 127, gg = tid >> 7;
    float acc[8];
#pragma unroll
    for (int n = 0; n < 8; n++) acc[n] = b[j];  // bias contributes once per node
    for (int k = 0; k < 64; k++) {
        float wv = W[k * OUT_DIM + j];
#pragma unroll
        for (int n = 0; n < 8; n++) acc[n] = fmaf(sH[(gg * 8 + n) * 64 + k], wv, acc[n]);
    }
    // flush runs of equal batch id with one atomic each (batch is sorted)
    float run = 0.f; int curb = -2;
#pragma unroll
    for (int n = 0; n < 8; n++) {
        int node = base + gg * 8 + n;
        int bb = (node < N_NODES) ? sB[gg * 8 + n] : -1;
        if (bb != curb) {
            if (curb >= 0) atomicAdd(&out[curb * OUT_DIM + j], run);
            run = 0.f; curb = bb;
        }
        if (bb >= 0) run += acc[n];
    }
    if (curb >= 0) atomicAdd(&out[curb * OUT_DIM + j], run);
}

extern "C" void kernel_launch(void* const* d_in, const int* in_sizes, int n_in,
                              void* d_out, int out_size, void* d_ws, size_t ws_size,
                              hipStream_t stream) {
    const int*   x        = (const int*)d_in[0];
    const int*   edge     = (const int*)d_in[1];
    const int*   batch    = (const int*)d_in[2];
    const float* embed    = (const float*)d_in[4];
    const float* lin_W    = (const float*)d_in[5];
    const float* lin_b    = (const float*)d_in[6];
    const float* gat_Wl   = (const float*)d_in[7];
    const float* gat_bl   = (const float*)d_in[8];
    const float* gat_Wr   = (const float*)d_in[9];
    const float* gat_br   = (const float*)d_in[10];
    const float* gat_att  = (const float*)d_in[11];
    const float* gat_bias = (const float*)d_in[12];
    const float* ro_W     = (const float*)d_in[13];
    const float* ro_b     = (const float*)d_in[14];
    float* out = (float*)d_out;

    const int* srcs = edge;
    const int* dsts = edge + E_EDGES;

    // workspace layout
    float* h  = (float*)d_ws;                       // N*64
    float* xl = h  + (size_t)N_NODES * 64;          // N*128 (head-interleaved)
    float* xr = xl + (size_t)N_NODES * HC;          // N*128 (head-interleaved)
    int* counts     = (int*)(xr + (size_t)N_NODES * HC);  // N
    int* row_ptr    = counts + N_NODES;                   // N+1
    int* write_off  = row_ptr + N_NODES + 1;              // N
    int* src_sorted = write_off + N_NODES;                // E_TOT

    const int T = 256;
    const int gEmbed = (N_NODES * C_DIM + 255) / 256;  // 12500
    const int gNode  = (N_NODES + 255) / 256;          // 196
    const int gEdge  = (E_TOT + 255) / 256;            // 3321
    const int gLin   = (N_NODES + 15) / 16;            // 3125
    const int gGat   = (N_NODES + 3) / 4;              // 12500
    const int gOut   = (G_GRAPHS * OUT_DIM + 255) / 256;

    embed_kernel<<<gEmbed, T, 0, stream>>>(x, embed, h);

    csr_zero_kernel<<<gNode, T, 0, stream>>>(counts);
    csr_count_kernel<<<gEdge, T, 0, stream>>>(dsts, counts);
    csr_scan_kernel<<<1, 1024, 0, stream>>>(counts, row_ptr, write_off);
    csr_scatter_kernel<<<gEdge, T, 0, stream>>>(srcs, dsts, write_off, src_sorted);

    for (int l = 0; l < L_LAYERS; l++) {
        layer_lin_kernel<<<gLin, T, 0, stream>>>(
            h,
            lin_W + (size_t)l * 64 * 64, lin_b + (size_t)l * 64,
            gat_Wl + (size_t)l * 64 * 128, gat_bl + (size_t)l * 128,
            gat_Wr + (size_t)l * 64 * 128, gat_br + (size_t)l * 128,
            xl, xr);
        gat_kernel<<<gGat, T, 0, stream>>>(
            (const float2*)xl, (const float2*)xr, gat_att + (size_t)l * HC,
            row_ptr, src_sorted, gat_bias + (size_t)l * 64, h);
    }

    zero_out_kernel<<<gOut, T, 0, stream>>>(out);
    readout_kernel<<<gLin, T, 0, stream>>>(h, ro_W, ro_b, batch, out);
}

// Round 4
// 633.751 us; speedup vs baseline: 4.1855x; 1.2570x over previous
//
#include <hip/hip_runtime.h>

#define N_NODES  50000
#define E_EDGES  800000
#define E_TOT    850000   // E + N self-loops
#define H_HEADS  2
#define C_DIM    64
#define HC       128
#define L_LAYERS 3
#define OUT_DIM  128
#define G_GRAPHS 512
#define NEG_SLOPE 0.2f

__device__ __forceinline__ void lds_fence() { asm volatile("" ::: "memory"); }

// ---- h[n][c] = embed[x[n]][c] ----
__global__ void embed_kernel(const int* __restrict__ x, const float* __restrict__ embed,
                             float* __restrict__ h) {
    int i = blockIdx.x * 256 + threadIdx.x;
    if (i >= N_NODES * C_DIM) return;
    int n = i >> 6, c = i & 63;
    h[i] = embed[x[n] * C_DIM + c];
}

// ---- CSR build ----
__global__ void csr_zero_kernel(int* __restrict__ counts) {
    int i = blockIdx.x * 256 + threadIdx.x;
    if (i < N_NODES) counts[i] = 0;
}

__global__ void csr_count_kernel(const int* __restrict__ dsts, int* __restrict__ counts) {
    int e = blockIdx.x * 256 + threadIdx.x;
    if (e >= E_TOT) return;
    int d = (e < E_EDGES) ? dsts[e] : e - E_EDGES;
    atomicAdd(&counts[d], 1);
}

__global__ void csr_scan_kernel(const int* __restrict__ counts, int* __restrict__ row_ptr,
                                int* __restrict__ write_off) {
    __shared__ int ssum[1024];
    int tid = threadIdx.x;
    const int CHUNK = (N_NODES + 1023) / 1024;  // 49
    int start = tid * CHUNK;
    int end = min(start + CHUNK, N_NODES);
    int s = 0;
    for (int i = start; i < end; i++) s += counts[i];
    ssum[tid] = s;
    __syncthreads();
    for (int off = 1; off < 1024; off <<= 1) {
        int v = (tid >= off) ? ssum[tid - off] : 0;
        __syncthreads();
        ssum[tid] += v;
        __syncthreads();
    }
    int run = (tid == 0) ? 0 : ssum[tid - 1];
    for (int i = start; i < end; i++) {
        row_ptr[i] = run;
        write_off[i] = run;
        run += counts[i];
    }
    if (tid == 1023) row_ptr[N_NODES] = run;
}

__global__ void csr_scatter_kernel(const int* __restrict__ srcs, const int* __restrict__ dsts,
                                   int* __restrict__ write_off, int* __restrict__ src_sorted) {
    int e = blockIdx.x * 256 + threadIdx.x;
    if (e >= E_TOT) return;
    int s, d;
    if (e < E_EDGES) { s = srcs[e]; d = dsts[e]; }
    else             { s = d = e - E_EDGES; }
    int pos = atomicAdd(&write_off[d], 1);
    src_sorted[pos] = s;
}

// ---- fused per-layer linears: h2 = relu(h@W+b); xl = h2@Wl+bl; xr = h2@Wr+br. ----
__global__ void layer_lin_kernel(const float* __restrict__ h,
                                 const float* __restrict__ W, const float* __restrict__ b,
                                 const float* __restrict__ Wl, const float* __restrict__ bl,
                                 const float* __restrict__ Wr, const float* __restrict__ br,
                                 float* __restrict__ xli, float* __restrict__ xri) {
    __shared__ float sH[16 * 64];
    __shared__ float sH2[16 * 64];
    int tid = threadIdx.x;
    int base = blockIdx.x * 16;
#pragma unroll
    for (int i = 0; i < 4; i++) {
        int idx = tid + i * 256;
        int nn = base + (idx >> 6);
        sH[idx] = (nn < N_NODES) ? h[(size_t)nn * 64 + (idx & 63)] : 0.f;
    }
    __syncthreads();
    {
        int c = tid & 63, g = tid >> 6;
        float a0 = b[c], a1 = a0, a2 = a0, a3 = a0;
        for (int k = 0; k < 64; k++) {
            float wv = W[k * 64 + c];
            a0 = fmaf(sH[(g * 4 + 0) * 64 + k], wv, a0);
            a1 = fmaf(sH[(g * 4 + 1) * 64 + k], wv, a1);
            a2 = fmaf(sH[(g * 4 + 2) * 64 + k], wv, a2);
            a3 = fmaf(sH[(g * 4 + 3) * 64 + k], wv, a3);
        }
        sH2[(g * 4 + 0) * 64 + c] = fmaxf(a0, 0.f);
        sH2[(g * 4 + 1) * 64 + c] = fmaxf(a1, 0.f);
        sH2[(g * 4 + 2) * 64 + c] = fmaxf(a2, 0.f);
        sH2[(g * 4 + 3) * 64 + c] = fmaxf(a3, 0.f);
    }
    __syncthreads();
    {
        int j = tid & 127, gg = tid >> 7;
        float accl[8], accr[8];
#pragma unroll
        for (int n = 0; n < 8; n++) { accl[n] = bl[j]; accr[n] = br[j]; }
        for (int k = 0; k < 64; k++) {
            float wl = Wl[k * 128 + j], wr = Wr[k * 128 + j];
#pragma unroll
            for (int n = 0; n < 8; n++) {
                float hv = sH2[(gg * 8 + n) * 64 + k];
                accl[n] = fmaf(hv, wl, accl[n]);
                accr[n] = fmaf(hv, wr, accr[n]);
            }
        }
        int hh = j >> 6, c = j & 63;
#pragma unroll
        for (int n = 0; n < 8; n++) {
            int node = base + gg * 8 + n;
            if (node < N_NODES) {
                size_t o = (size_t)node * 128 + c * 2 + hh;
                xli[o] = accl[n];
                xri[o] = accr[n];
            }
        }
    }
}

// ---- GATv2 edge phase: one wave per dst node, lane = channel, float2 = both heads.
// 8-edge batches: register-held vl, LDS-transpose score reduction, batched softmax. ----
__global__ void gat_kernel(const float2* __restrict__ xl2, const float2* __restrict__ xr2,
                           const float* __restrict__ att, const int* __restrict__ row_ptr,
                           const int* __restrict__ src_sorted, const float* __restrict__ bias,
                           float* __restrict__ h_out) {
    __shared__ __align__(16) float cbuf[4][8 * 132];
    __shared__ float2 wbuf[4][8];
    int w = threadIdx.x >> 6;
    int d = blockIdx.x * 4 + w;
    if (d >= N_NODES) return;
    int lane = threadIdx.x & 63;
    int r0 = row_ptr[d], r1 = row_ptr[d + 1];
    float2 vr = xr2[(size_t)d * 64 + lane];
    float ax = att[lane], ay = att[64 + lane];
    float* cb = cbuf[w];
    float2* wb = wbuf[w];
    int e_of = lane >> 3, p = lane & 7;

    float mx = -INFINITY, my = -INFINITY;
    float dpx = 0.f, dpy = 0.f;     // per-lane denom partials (8 copies per edge -> /8 via final reduce)
    float accx = 0.f, accy = 0.f;

    for (int base = r0; base < r1; base += 64) {
        int a = base + lane;
        int idx = src_sorted[(a < r1) ? a : (r1 - 1)];   // coalesced superchunk stage
        for (int cbase = 0; cbase < 64 && base + cbase < r1; cbase += 8) {
            int rem = r1 - base - cbase;                 // >= 1, wave-uniform
            // --- gather 8 rows into registers (independent, latency-overlapped) ---
            float2 vl[8];
#pragma unroll
            for (int e = 0; e < 8; e++) {
                int sv = __builtin_amdgcn_readlane(idx, cbase + e);  // uniform src id
                int s = (e < rem) ? sv : d;
                vl[e] = xl2[(size_t)s * 64 + lane];
            }
            // --- elementwise contribution + transpose write ---
#pragma unroll
            for (int e = 0; e < 8; e++) {
                float vx = vl[e].x + vr.x, vy = vl[e].y + vr.y;
                vx = fmaxf(vx, vx * NEG_SLOPE);          // leaky relu
                vy = fmaxf(vy, vy * NEG_SLOPE);
                *(float2*)&cb[e * 132 + 2 * lane] = make_float2(vx * ax, vy * ay);
            }
            lds_fence();
            // --- transpose read: lane (e_of, p) sums 16 floats of edge e_of ---
            float sx = 0.f, sy = 0.f;
            {
                const float4* row = (const float4*)&cb[e_of * 132 + p * 16];
#pragma unroll
                for (int j = 0; j < 4; j++) {
                    float4 f = row[j];
                    sx += f.x + f.z;
                    sy += f.y + f.w;
                }
            }
            lds_fence();
            // combine 8 partials per edge (xor 1,2,4)
#pragma unroll
            for (int off = 1; off <= 4; off <<= 1) {
                sx += __shfl_xor(sx, off, 64);
                sy += __shfl_xor(sy, off, 64);
            }
            if (rem < 8) {                               // mask invalid edges
                if (e_of >= rem) { sx = -INFINITY; sy = -INFINITY; }
            }
            // chunk max (values uniform within 8-lane groups -> xor 8,16,32 only)
            float cmx = sx, cmy = sy;
#pragma unroll
            for (int off = 8; off <= 32; off <<= 1) {
                cmx = fmaxf(cmx, __shfl_xor(cmx, off, 64));
                cmy = fmaxf(cmy, __shfl_xor(cmy, off, 64));
            }
            // merge + rescale ONCE per 8 edges
            float nmx = fmaxf(mx, cmx), nmy = fmaxf(my, cmy);
            float scx = __expf(mx - nmx), scy = __expf(my - nmy);
            accx *= scx; accy *= scy;
            dpx *= scx;  dpy *= scy;
            mx = nmx; my = nmy;
            // per-lane weight for own edge
            float wx = __expf(sx - mx), wy = __expf(sy - my);
            dpx += wx; dpy += wy;
            if (p == 0) wb[e_of] = make_float2(wx, wy);
            lds_fence();
            // --- aggregation from register vl with broadcast weights ---
#pragma unroll
            for (int e = 0; e < 8; e++) {
                float2 wv = wb[e];
                accx = fmaf(wv.x, vl[e].x, accx);
                accy = fmaf(wv.y, vl[e].y, accy);
            }
            lds_fence();
        }
    }
    // final denom reduce: sum over 64 lanes = 8 * sum_e w_e
#pragma unroll
    for (int off = 32; off; off >>= 1) {
        dpx += __shfl_xor(dpx, off, 64);
        dpy += __shfl_xor(dpy, off, 64);
    }
    h_out[(size_t)d * 64 + lane] = (accx / dpx + accy / dpy) * 4.0f + bias[lane];
}

__global__ void zero_out_kernel(float* __restrict__ out) {
    int i = blockIdx.x * 256 + threadIdx.x;
    if (i < G_GRAPHS * OUT_DIM) out[i] = 0.f;
}

// ---- readout GEMM fused with per-graph segment sum; batch-sorted run grouping ----
__global__ void readout_kernel(const float* __restrict__ h, const float* __restrict__ W,
                               const float* __restrict__ b, const int* __restrict__ batch,
                               float* __restrict__ out) {
    __shared__ float sH[16 * 64];
    __shared__ int sB[16];
    int tid = threadIdx.x;
    int base = blockIdx.x * 16;
#pragma unroll
    for (int i = 0; i < 4; i++) {
        int idx = tid + i * 256;
        int nn = base + (idx >> 6);
        sH[idx] = (nn < N_NODES) ? h[(size_t)nn * 64 + (idx & 63)] : 0.f;
    }
    if (tid < 16) sB[tid] = (base + tid < N_NODES) ? batch[base + tid] : -1;
    __syncthreads();
    int j = tid & 127, gg = tid >> 7;
    float acc[8];
#pragma unroll
    for (int n = 0; n < 8; n++) acc[n] = b[j];
    for (int k = 0; k < 64; k++) {
        float wv = W[k * OUT_DIM + j];
#pragma unroll
        for (int n = 0; n < 8; n++) acc[n] = fmaf(sH[(gg * 8 + n) * 64 + k], wv, acc[n]);
    }
    float run = 0.f; int curb = -2;
#pragma unroll
    for (int n = 0; n < 8; n++) {
        int node = base + gg * 8 + n;
        int bb = (node < N_NODES) ? sB[gg * 8 + n] : -1;
        if (bb != curb) {
            if (curb >= 0) atomicAdd(&out[curb * OUT_DIM + j], run);
            run = 0.f; curb = bb;
        }
        if (bb >= 0) run += acc[n];
    }
    if (curb >= 0) atomicAdd(&out[curb * OUT_DIM + j], run);
}

extern "C" void kernel_launch(void* const* d_in, const int* in_sizes, int n_in,
                              void* d_out, int out_size, void* d_ws, size_t ws_size,
                              hipStream_t stream) {
    const int*   x        = (const int*)d_in[0];
    const int*   edge     = (const int*)d_in[1];
    const int*   batch    = (const int*)d_in[2];
    const float* embed    = (const float*)d_in[4];
    const float* lin_W    = (const float*)d_in[5];
    const float* lin_b    = (const float*)d_in[6];
    const float* gat_Wl   = (const float*)d_in[7];
    const float* gat_bl   = (const float*)d_in[8];
    const float* gat_Wr   = (const float*)d_in[9];
    const float* gat_br   = (const float*)d_in[10];
    const float* gat_att  = (const float*)d_in[11];
    const float* gat_bias = (const float*)d_in[12];
    const float* ro_W     = (const float*)d_in[13];
    const float* ro_b     = (const float*)d_in[14];
    float* out = (float*)d_out;

    const int* srcs = edge;
    const int* dsts = edge + E_EDGES;

    float* h  = (float*)d_ws;
    float* xl = h  + (size_t)N_NODES * 64;
    float* xr = xl + (size_t)N_NODES * HC;
    int* counts     = (int*)(xr + (size_t)N_NODES * HC);
    int* row_ptr    = counts + N_NODES;
    int* write_off  = row_ptr + N_NODES + 1;
    int* src_sorted = write_off + N_NODES;

    const int T = 256;
    const int gEmbed = (N_NODES * C_DIM + 255) / 256;
    const int gNode  = (N_NODES + 255) / 256;
    const int gEdge  = (E_TOT + 255) / 256;
    const int gLin   = (N_NODES + 15) / 16;
    const int gGat   = (N_NODES + 3) / 4;
    const int gOut   = (G_GRAPHS * OUT_DIM + 255) / 256;

    embed_kernel<<<gEmbed, T, 0, stream>>>(x, embed, h);

    csr_zero_kernel<<<gNode, T, 0, stream>>>(counts);
    csr_count_kernel<<<gEdge, T, 0, stream>>>(dsts, counts);
    csr_scan_kernel<<<1, 1024, 0, stream>>>(counts, row_ptr, write_off);
    csr_scatter_kernel<<<gEdge, T, 0, stream>>>(srcs, dsts, write_off, src_sorted);

    for (int l = 0; l < L_LAYERS; l++) {
        layer_lin_kernel<<<gLin, T, 0, stream>>>(
            h,
            lin_W + (size_t)l * 64 * 64, lin_b + (size_t)l * 64,
            gat_Wl + (size_t)l * 64 * 128, gat_bl + (size_t)l * 128,
            gat_Wr + (size_t)l * 64 * 128, gat_br + (size_t)l * 128,
            xl, xr);
        gat_kernel<<<gGat, T, 0, stream>>>(
            (const float2*)xl, (const float2*)xr, gat_att + (size_t)l * HC,
            row_ptr, src_sorted, gat_bias + (size_t)l * 64, h);
    }

    zero_out_kernel<<<gOut, T, 0, stream>>>(out);
    readout_kernel<<<gLin, T, 0, stream>>>(h, ro_W, ro_b, batch, out);
}

// Round 5
// 532.663 us; speedup vs baseline: 4.9799x; 1.1898x over previous
//
#include <hip/hip_runtime.h>

#define N_NODES  50000
#define E_EDGES  800000
#define E_TOT    850000   // E + N self-loops
#define H_HEADS  2
#define C_DIM    64
#define HC       128
#define L_LAYERS 3
#define OUT_DIM  128
#define G_GRAPHS 512
#define NEG_SLOPE 0.2f
#define SCAN_B   196      // ceil(N/256)

__device__ __forceinline__ void lds_fence() { asm volatile("" ::: "memory"); }

// ---- h[n][c] = embed[x[n]][c] ----
__global__ void embed_kernel(const int* __restrict__ x, const float* __restrict__ embed,
                             float* __restrict__ h) {
    int i = blockIdx.x * 256 + threadIdx.x;
    if (i >= N_NODES * C_DIM) return;
    int n = i >> 6, c = i & 63;
    h[i] = embed[x[n] * C_DIM + c];
}

// ---- CSR build ----
__global__ void csr_zero_kernel(int* __restrict__ counts) {
    int i = blockIdx.x * 256 + threadIdx.x;
    if (i < N_NODES) counts[i] = 0;
}

__global__ void csr_count_kernel(const int* __restrict__ dsts, int* __restrict__ counts) {
    int e = blockIdx.x * 256 + threadIdx.x;
    if (e >= E_TOT) return;
    int d = (e < E_EDGES) ? dsts[e] : e - E_EDGES;
    atomicAdd(&counts[d], 1);
}

// phase 1: block-local exclusive scan of counts; per-block totals
__global__ void scan_partial_kernel(const int* __restrict__ counts, int* __restrict__ row_ptr,
                                    int* __restrict__ partials) {
    __shared__ int wsum[4];
    int i = blockIdx.x * 256 + threadIdx.x;
    int lane = threadIdx.x & 63, wid = threadIdx.x >> 6;
    int cnt = (i < N_NODES) ? counts[i] : 0;
    int v = cnt;
#pragma unroll
    for (int off = 1; off < 64; off <<= 1) {
        int t = __shfl_up(v, off, 64);
        if (lane >= off) v += t;
    }
    if (lane == 63) wsum[wid] = v;
    __syncthreads();
    int woff = 0;
#pragma unroll
    for (int w = 0; w < 4; w++) if (w < wid) woff += wsum[w];
    v += woff;
    if (i < N_NODES) row_ptr[i] = v - cnt;   // block-local exclusive
    if (threadIdx.x == 255) partials[blockIdx.x] = v;  // block total
}

// phase 2: single small block scans the SCAN_B partials -> exclusive block offsets
__global__ void scan_offsets_kernel(const int* __restrict__ partials, int* __restrict__ block_off) {
    __shared__ int wsum[4];
    int tid = threadIdx.x;
    int lane = tid & 63, wid = tid >> 6;
    int cnt = (tid < SCAN_B) ? partials[tid] : 0;
    int v = cnt;
#pragma unroll
    for (int off = 1; off < 64; off <<= 1) {
        int t = __shfl_up(v, off, 64);
        if (lane >= off) v += t;
    }
    if (lane == 63) wsum[wid] = v;
    __syncthreads();
    int woff = 0;
#pragma unroll
    for (int w = 0; w < 4; w++) if (w < wid) woff += wsum[w];
    v += woff;
    if (tid < SCAN_B) block_off[tid] = v - cnt;
}

// phase 3: add block offsets; mirror to write_off; row_ptr[N] = E_TOT
__global__ void scan_add_kernel(int* __restrict__ row_ptr, const int* __restrict__ block_off,
                                int* __restrict__ write_off) {
    int i = blockIdx.x * 256 + threadIdx.x;
    if (i < N_NODES) {
        int v = row_ptr[i] + block_off[blockIdx.x];
        row_ptr[i] = v;
        write_off[i] = v;
    }
    if (i == 0) row_ptr[N_NODES] = E_TOT;
}

__global__ void csr_scatter_kernel(const int* __restrict__ srcs, const int* __restrict__ dsts,
                                   int* __restrict__ write_off, int* __restrict__ src_sorted) {
    int e = blockIdx.x * 256 + threadIdx.x;
    if (e >= E_TOT) return;
    int s, d;
    if (e < E_EDGES) { s = srcs[e]; d = dsts[e]; }
    else             { s = d = e - E_EDGES; }
    int pos = atomicAdd(&write_off[d], 1);
    src_sorted[pos] = s;
}

// ---- fused per-layer linears: h2 = relu(h@W+b); xl = h2@Wl+bl; xr = h2@Wr+br. ----
__global__ void layer_lin_kernel(const float* __restrict__ h,
                                 const float* __restrict__ W, const float* __restrict__ b,
                                 const float* __restrict__ Wl, const float* __restrict__ bl,
                                 const float* __restrict__ Wr, const float* __restrict__ br,
                                 float* __restrict__ xli, float* __restrict__ xri) {
    __shared__ float sH[16 * 64];
    __shared__ float sH2[16 * 64];
    int tid = threadIdx.x;
    int base = blockIdx.x * 16;
#pragma unroll
    for (int i = 0; i < 4; i++) {
        int idx = tid + i * 256;
        int nn = base + (idx >> 6);
        sH[idx] = (nn < N_NODES) ? h[(size_t)nn * 64 + (idx & 63)] : 0.f;
    }
    __syncthreads();
    {
        int c = tid & 63, g = tid >> 6;
        float a0 = b[c], a1 = a0, a2 = a0, a3 = a0;
        for (int k = 0; k < 64; k++) {
            float wv = W[k * 64 + c];
            a0 = fmaf(sH[(g * 4 + 0) * 64 + k], wv, a0);
            a1 = fmaf(sH[(g * 4 + 1) * 64 + k], wv, a1);
            a2 = fmaf(sH[(g * 4 + 2) * 64 + k], wv, a2);
            a3 = fmaf(sH[(g * 4 + 3) * 64 + k], wv, a3);
        }
        sH2[(g * 4 + 0) * 64 + c] = fmaxf(a0, 0.f);
        sH2[(g * 4 + 1) * 64 + c] = fmaxf(a1, 0.f);
        sH2[(g * 4 + 2) * 64 + c] = fmaxf(a2, 0.f);
        sH2[(g * 4 + 3) * 64 + c] = fmaxf(a3, 0.f);
    }
    __syncthreads();
    {
        int j = tid & 127, gg = tid >> 7;
        float accl[8], accr[8];
#pragma unroll
        for (int n = 0; n < 8; n++) { accl[n] = bl[j]; accr[n] = br[j]; }
        for (int k = 0; k < 64; k++) {
            float wl = Wl[k * 128 + j], wr = Wr[k * 128 + j];
#pragma unroll
            for (int n = 0; n < 8; n++) {
                float hv = sH2[(gg * 8 + n) * 64 + k];
                accl[n] = fmaf(hv, wl, accl[n]);
                accr[n] = fmaf(hv, wr, accr[n]);
            }
        }
        int hh = j >> 6, c = j & 63;
#pragma unroll
        for (int n = 0; n < 8; n++) {
            int node = base + gg * 8 + n;
            if (node < N_NODES) {
                size_t o = (size_t)node * 128 + c * 2 + hh;
                xli[o] = accl[n];
                xri[o] = accr[n];
            }
        }
    }
}

// ---- GATv2 edge phase: one wave per dst node, lane = channel, float2 = both heads.
// 8-edge batches: register-held vl, LDS-transpose score reduction, batched softmax. ----
__global__ void gat_kernel(const float2* __restrict__ xl2, const float2* __restrict__ xr2,
                           const float* __restrict__ att, const int* __restrict__ row_ptr,
                           const int* __restrict__ src_sorted, const float* __restrict__ bias,
                           float* __restrict__ h_out) {
    __shared__ __align__(16) float cbuf[4][8 * 132];
    __shared__ float2 wbuf[4][8];
    int w = threadIdx.x >> 6;
    int d = blockIdx.x * 4 + w;
    if (d >= N_NODES) return;
    int lane = threadIdx.x & 63;
    int r0 = row_ptr[d], r1 = row_ptr[d + 1];
    float2 vr = xr2[(size_t)d * 64 + lane];
    float ax = att[lane], ay = att[64 + lane];
    float* cb = cbuf[w];
    float2* wb = wbuf[w];
    int e_of = lane >> 3, p = lane & 7;

    float mx = -INFINITY, my = -INFINITY;
    float dpx = 0.f, dpy = 0.f;
    float accx = 0.f, accy = 0.f;

    for (int base = r0; base < r1; base += 64) {
        int a = base + lane;
        int idx = src_sorted[(a < r1) ? a : (r1 - 1)];
        for (int cbase = 0; cbase < 64 && base + cbase < r1; cbase += 8) {
            int rem = r1 - base - cbase;
            float2 vl[8];
#pragma unroll
            for (int e = 0; e < 8; e++) {
                int sv = __builtin_amdgcn_readlane(idx, cbase + e);
                int s = (e < rem) ? sv : d;
                vl[e] = xl2[(size_t)s * 64 + lane];
            }
#pragma unroll
            for (int e = 0; e < 8; e++) {
                float vx = vl[e].x + vr.x, vy = vl[e].y + vr.y;
                vx = fmaxf(vx, vx * NEG_SLOPE);
                vy = fmaxf(vy, vy * NEG_SLOPE);
                *(float2*)&cb[e * 132 + 2 * lane] = make_float2(vx * ax, vy * ay);
            }
            lds_fence();
            float sx = 0.f, sy = 0.f;
            {
                const float4* row = (const float4*)&cb[e_of * 132 + p * 16];
#pragma unroll
                for (int j = 0; j < 4; j++) {
                    float4 f = row[j];
                    sx += f.x + f.z;
                    sy += f.y + f.w;
                }
            }
            lds_fence();
#pragma unroll
            for (int off = 1; off <= 4; off <<= 1) {
                sx += __shfl_xor(sx, off, 64);
                sy += __shfl_xor(sy, off, 64);
            }
            if (rem < 8) {
                if (e_of >= rem) { sx = -INFINITY; sy = -INFINITY; }
            }
            float cmx = sx, cmy = sy;
#pragma unroll
            for (int off = 8; off <= 32; off <<= 1) {
                cmx = fmaxf(cmx, __shfl_xor(cmx, off, 64));
                cmy = fmaxf(cmy, __shfl_xor(cmy, off, 64));
            }
            float nmx = fmaxf(mx, cmx), nmy = fmaxf(my, cmy);
            float scx = __expf(mx - nmx), scy = __expf(my - nmy);
            accx *= scx; accy *= scy;
            dpx *= scx;  dpy *= scy;
            mx = nmx; my = nmy;
            float wx = __expf(sx - mx), wy = __expf(sy - my);
            dpx += wx; dpy += wy;
            if (p == 0) wb[e_of] = make_float2(wx, wy);
            lds_fence();
#pragma unroll
            for (int e = 0; e < 8; e++) {
                float2 wv = wb[e];
                accx = fmaf(wv.x, vl[e].x, accx);
                accy = fmaf(wv.y, vl[e].y, accy);
            }
            lds_fence();
        }
    }
#pragma unroll
    for (int off = 32; off; off >>= 1) {
        dpx += __shfl_xor(dpx, off, 64);
        dpy += __shfl_xor(dpy, off, 64);
    }
    h_out[(size_t)d * 64 + lane] = (accx / dpx + accy / dpy) * 4.0f + bias[lane];
}

__global__ void zero_out_kernel(float* __restrict__ out) {
    int i = blockIdx.x * 256 + threadIdx.x;
    if (i < G_GRAPHS * OUT_DIM) out[i] = 0.f;
}

// ---- readout GEMM fused with per-graph segment sum; batch-sorted run grouping ----
__global__ void readout_kernel(const float* __restrict__ h, const float* __restrict__ W,
                               const float* __restrict__ b, const int* __restrict__ batch,
                               float* __restrict__ out) {
    __shared__ float sH[16 * 64];
    __shared__ int sB[16];
    int tid = threadIdx.x;
    int base = blockIdx.x * 16;
#pragma unroll
    for (int i = 0; i < 4; i++) {
        int idx = tid + i * 256;
        int nn = base + (idx >> 6);
        sH[idx] = (nn < N_NODES) ? h[(size_t)nn * 64 + (idx & 63)] : 0.f;
    }
    if (tid < 16) sB[tid] = (base + tid < N_NODES) ? batch[base + tid] : -1;
    __syncthreads();
    int j = tid & 127, gg = tid >> 7;
    float acc[8];
#pragma unroll
    for (int n = 0; n < 8; n++) acc[n] = b[j];
    for (int k = 0; k < 64; k++) {
        float wv = W[k * OUT_DIM + j];
#pragma unroll
        for (int n = 0; n < 8; n++) acc[n] = fmaf(sH[(gg * 8 + n) * 64 + k], wv, acc[n]);
    }
    float run = 0.f; int curb = -2;
#pragma unroll
    for (int n = 0; n < 8; n++) {
        int node = base + gg * 8 + n;
        int bb = (node < N_NODES) ? sB[gg * 8 + n] : -1;
        if (bb != curb) {
            if (curb >= 0) atomicAdd(&out[curb * OUT_DIM + j], run);
            run = 0.f; curb = bb;
        }
        if (bb >= 0) run += acc[n];
    }
    if (curb >= 0) atomicAdd(&out[curb * OUT_DIM + j], run);
}

extern "C" void kernel_launch(void* const* d_in, const int* in_sizes, int n_in,
                              void* d_out, int out_size, void* d_ws, size_t ws_size,
                              hipStream_t stream) {
    const int*   x        = (const int*)d_in[0];
    const int*   edge     = (const int*)d_in[1];
    const int*   batch    = (const int*)d_in[2];
    const float* embed    = (const float*)d_in[4];
    const float* lin_W    = (const float*)d_in[5];
    const float* lin_b    = (const float*)d_in[6];
    const float* gat_Wl   = (const float*)d_in[7];
    const float* gat_bl   = (const float*)d_in[8];
    const float* gat_Wr   = (const float*)d_in[9];
    const float* gat_br   = (const float*)d_in[10];
    const float* gat_att  = (const float*)d_in[11];
    const float* gat_bias = (const float*)d_in[12];
    const float* ro_W     = (const float*)d_in[13];
    const float* ro_b     = (const float*)d_in[14];
    float* out = (float*)d_out;

    const int* srcs = edge;
    const int* dsts = edge + E_EDGES;

    float* h  = (float*)d_ws;
    float* xl = h  + (size_t)N_NODES * 64;
    float* xr = xl + (size_t)N_NODES * HC;
    int* counts     = (int*)(xr + (size_t)N_NODES * HC);
    int* row_ptr    = counts + N_NODES;
    int* write_off  = row_ptr + N_NODES + 1;
    int* src_sorted = write_off + N_NODES;
    int* partials   = src_sorted + E_TOT;    // SCAN_B
    int* block_off  = partials + SCAN_B;     // SCAN_B

    const int T = 256;
    const int gEmbed = (N_NODES * C_DIM + 255) / 256;
    const int gNode  = (N_NODES + 255) / 256;   // == SCAN_B
    const int gEdge  = (E_TOT + 255) / 256;
    const int gLin   = (N_NODES + 15) / 16;
    const int gGat   = (N_NODES + 3) / 4;
    const int gOut   = (G_GRAPHS * OUT_DIM + 255) / 256;

    embed_kernel<<<gEmbed, T, 0, stream>>>(x, embed, h);

    csr_zero_kernel<<<gNode, T, 0, stream>>>(counts);
    csr_count_kernel<<<gEdge, T, 0, stream>>>(dsts, counts);
    scan_partial_kernel<<<SCAN_B, T, 0, stream>>>(counts, row_ptr, partials);
    scan_offsets_kernel<<<1, T, 0, stream>>>(partials, block_off);
    scan_add_kernel<<<SCAN_B, T, 0, stream>>>(row_ptr, block_off, write_off);
    csr_scatter_kernel<<<gEdge, T, 0, stream>>>(srcs, dsts, write_off, src_sorted);

    for (int l = 0; l < L_LAYERS; l++) {
        layer_lin_kernel<<<gLin, T, 0, stream>>>(
            h,
            lin_W + (size_t)l * 64 * 64, lin_b + (size_t)l * 64,
            gat_Wl + (size_t)l * 64 * 128, gat_bl + (size_t)l * 128,
            gat_Wr + (size_t)l * 64 * 128, gat_br + (size_t)l * 128,
            xl, xr);
        gat_kernel<<<gGat, T, 0, stream>>>(
            (const float2*)xl, (const float2*)xr, gat_att + (size_t)l * HC,
            row_ptr, src_sorted, gat_bias + (size_t)l * 64, h);
    }

    zero_out_kernel<<<gOut, T, 0, stream>>>(out);
    readout_kernel<<<gLin, T, 0, stream>>>(h, ro_W, ro_b, batch, out);
}